// Round 5
// baseline (412.388 us; speedup 1.0000x reference)
//
#include <hip/hip_runtime.h>
#include <math.h>

// FHN dynamics — R4 kernel + MEASUREMENT PROBE.
// The fhn dispatch (~157 us by decomposition) sits just below rocprof's
// top-5 duration cutoff (~163 us, all ws-poison fills), so its counters
// have never been visible. This round adds a dependent-FMA pad
// (768 FMAs, issue-bound ~ +41 us device-wide) purely to push the
// dispatch into the top-5 and read FETCH_SIZE / WRITE_SIZE / hbm_gbps.
// Memory behavior is byte-identical to R4. Pad is DCE-proofed with
// asm volatile and will be removed next round.

#define ROWLEN 2048
#define BLOCK  256
#define EPT    8                 // elements per thread
#define F4PT   (EPT / 4)         // float4 loads per thread = 2
#define PROBE_PAD 768            // dependent FMAs; ~41 us device-wide

__global__ __launch_bounds__(BLOCK)
void fhn_kernel(const float* __restrict__ stim,
                const float* __restrict__ a_p,
                const float* __restrict__ b_p,
                const float* __restrict__ dt_p,
                const int*   __restrict__ nsteps_p,
                float* __restrict__ out,      // [n_elem] response, then [n_elem] v
                long long n_elem)
{
    const long long row = blockIdx.x;
    const float* __restrict__ srow = stim + row * ROWLEN;
    float* __restrict__ rrow = out + row * ROWLEN;
    float* __restrict__ vrow = out + n_elem + row * ROWLEN;

    const int tid = threadIdx.x;

    // ---- coalesced float4 loads: lane t takes float4 slots {t, t+256} ----
    float s[EPT];
    #pragma unroll
    for (int i = 0; i < F4PT; ++i) {
        float4 f = reinterpret_cast<const float4*>(srow)[tid + i * BLOCK];
        s[4*i+0] = f.x; s[4*i+1] = f.y; s[4*i+2] = f.z; s[4*i+3] = f.w;
    }

    // ---- row max(|s|): local -> wave butterfly -> cross-wave via LDS ----
    float m = 0.0f;
    #pragma unroll
    for (int e = 0; e < EPT; ++e) m = fmaxf(m, fabsf(s[e]));
    #pragma unroll
    for (int off = 32; off > 0; off >>= 1)
        m = fmaxf(m, __shfl_xor(m, off, 64));
    __shared__ float smax[BLOCK / 64];
    if ((tid & 63) == 0) smax[tid >> 6] = m;
    __syncthreads();
    m = fmaxf(fmaxf(smax[0], smax[1]), fmaxf(smax[2], smax[3]));

    const float scale     = fmaxf(m, 1e-6f);
    const float inv_scale = 1.0f / scale;

    // ---- scalar params (device-resident 1-element arrays) ----
    const float a  = *a_p;
    const float b  = *b_p;
    const float dt = *dt_p;
    const int   n_steps = *nsteps_p;
    const float alpha     = dt / 12.5f;        // TAU = 12.5
    const float inv_denom = 1.0f / (1.0f + alpha * b);

    // folded step constants
    const float c1 = 1.0f + dt;
    const float c2 = dt * (1.0f / 3.0f);
    const float kw = inv_denom;                // w' = kw*w + k1*vn + k2
    const float k1 = alpha * inv_denom;
    const float k2 = alpha * a * inv_denom;
    const float premul = dt * inv_scale;       // we only ever need dt*I

    // ---- conditioned input current dt*I; v = w = 0 ----
    float dtI[EPT], v[EPT], w[EPT];
    #pragma unroll
    for (int e = 0; e < EPT; ++e) {
        const float as  = fabsf(s[e]);
        const float E   = __expf(fmaf(-10.0f, as, 5.0f));   // exp(-(|s|-0.5)*10)
        const float num = fmaf(0.1f, E, 1.0f);              // 1 + 0.1E
        const float rd  = __builtin_amdgcn_rcpf(1.0f + E);  // ~1ulp, tol=0.0625
        dtI[e] = s[e] * premul * num * rd;                  // s*(0.1+0.9*sig)*dt/scale
        v[e] = 0.0f;
        w[e] = 0.0f;
    }

    // ---- IMEX FHN steps: 8 VALU ops per elem per step ----
    for (int n = 0; n < n_steps; ++n) {
        #pragma unroll
        for (int e = 0; e < EPT; ++e) {
            const float ve = v[e], we = w[e];
            const float t  = ve * ve;                  // v^2
            const float u  = fmaf(-dt, we, dtI[e]);    // dt*I - dt*w
            const float p  = fmaf(c1, ve, u);          // (1+dt)v + ...
            const float q  = c2 * t;                   // (dt/3) v^2
            const float vn = fmaf(-q, ve, p);          // unclipped v_next
            v[e] = fminf(fmaxf(vn, -3.0f), 3.0f);      // med3
            w[e] = fmaf(kw, we, fmaf(k1, vn, k2));     // unclipped vn (matches ref)
        }
    }

    // ---- PROBE PAD: dependent FMA chain, issue-bound ~41 us device-wide.
    // Pushes this dispatch above the top-5 cutoff so counters show up.
    {
        float x = scale;
        #pragma unroll
        for (int p = 0; p < PROBE_PAD; ++p)
            x = fmaf(x, 1.0000001f, 1e-30f);
        asm volatile("" :: "v"(x));    // keep live, rule #17
    }

    // ---- epilogue: response = v * scale; also emit v (plain stores) ----
    #pragma unroll
    for (int i = 0; i < F4PT; ++i) {
        float4 r, vv;
        r.x  = v[4*i+0] * scale; r.y  = v[4*i+1] * scale;
        r.z  = v[4*i+2] * scale; r.w  = v[4*i+3] * scale;
        vv.x = v[4*i+0];         vv.y = v[4*i+1];
        vv.z = v[4*i+2];         vv.w = v[4*i+3];
        reinterpret_cast<float4*>(rrow)[tid + i * BLOCK] = r;
        reinterpret_cast<float4*>(vrow)[tid + i * BLOCK] = vv;
    }
}

extern "C" void kernel_launch(void* const* d_in, const int* in_sizes, int n_in,
                              void* d_out, int out_size, void* d_ws, size_t ws_size,
                              hipStream_t stream) {
    const float* stim = (const float*)d_in[0];
    const float* a_p  = (const float*)d_in[1];
    const float* b_p  = (const float*)d_in[2];
    const float* dt_p = (const float*)d_in[3];
    const int*   n_p  = (const int*)d_in[4];
    float* out = (float*)d_out;

    const long long n_elem = (long long)in_sizes[0];
    const int rows = (int)(n_elem / ROWLEN);
    if (rows <= 0) return;

    fhn_kernel<<<rows, BLOCK, 0, stream>>>(stim, a_p, b_p, dt_p, n_p, out, n_elem);
}